// Round 6
// baseline (312.313 us; speedup 1.0000x reference)
//
#include <hip/hip_runtime.h>
#include <hip/hip_bf16.h>
#include <hip/hip_fp16.h>

#define N_NODES 50000
#define N_EDGES 1600000
#define NPB    50      // nodes per bucket
#define NBUK   1000    // NPB*NBUK == N_NODES
#define NSL    8       // XCD slices
#define BCAPS  320     // slots per (bucket,slice): mean 200, +8.5 sigma
#define MAXE   2560    // NSL*BCAPS, max edges per bucket
#define GEMMB  782     // GEMM blocks in fused kernel
#define PARTB  256     // partition blocks in fused kernel
#define CHUNK  6250    // edges per partition block (256*6250 = 1.6M)
#define BD     10      // LDS bin depth (lambda=6.25, overflow ~0.5% -> fallback)

typedef __attribute__((ext_vector_type(8))) short short8;
typedef __attribute__((ext_vector_type(4))) float f32x4;

__device__ __forceinline__ unsigned short f2bf(float f) {
  union { float f; unsigned int i; } v; v.f = f;
  unsigned int i = v.i;
  unsigned int r = i + 0x7FFFu + ((i >> 16) & 1u);
  return (unsigned short)(r >> 16);
}

// ---------------- Kernel 1: FUSED  x = h @ W  +  edge partition -------------
// Blocks [0,782): bf16-MFMA GEMM. Blocks [782,1038): LDS-binned partition.
// Data-independent chains fused so the latency-bound atomic work hides under
// the MFMA waves. (Round-4 win: k_part 75us -> invisible.)
__global__ __launch_bounds__(256) void k_xpart(const float* __restrict__ hmat,
    const float* __restrict__ Wmat, float* __restrict__ x,
    const int* __restrict__ ei, int* __restrict__ bcnt,
    unsigned int* __restrict__ raw) {
  __shared__ __align__(16) char smem[44032];
  const int t = threadIdx.x;
  if (blockIdx.x < GEMMB) {
    // ---- GEMM path (unchanged) ----
    unsigned short* Wt = (unsigned short*)smem;   // Wt[n][k], row stride 264
    for (int idx = t; idx < 64 * 256; idx += 256) {
      int k = idx >> 6, n = idx & 63;
      Wt[n * 264 + k] = f2bf(Wmat[idx]);
    }
    __syncthreads();
    const int wave = t >> 6, lane = t & 63;
    const int quad = lane >> 4, l16 = lane & 15;
    const int m0 = blockIdx.x * 64 + wave * 16;
    int arow = m0 + l16; if (arow >= N_NODES) arow = N_NODES - 1;
    f32x4 c[4] = {{0,0,0,0},{0,0,0,0},{0,0,0,0},{0,0,0,0}};
    const float* aptr = hmat + (size_t)arow * 256 + quad * 8;
    #pragma unroll
    for (int kb = 0; kb < 8; ++kb) {
      f32x4 a0 = *(const f32x4*)(aptr + kb * 32);
      f32x4 a1 = *(const f32x4*)(aptr + kb * 32 + 4);
      short8 a;
      a[0] = (short)f2bf(a0[0]); a[1] = (short)f2bf(a0[1]);
      a[2] = (short)f2bf(a0[2]); a[3] = (short)f2bf(a0[3]);
      a[4] = (short)f2bf(a1[0]); a[5] = (short)f2bf(a1[1]);
      a[6] = (short)f2bf(a1[2]); a[7] = (short)f2bf(a1[3]);
      #pragma unroll
      for (int nt = 0; nt < 4; ++nt) {
        int n = nt * 16 + l16;
        short8 b = *(const short8*)(&Wt[n * 264 + kb * 32 + quad * 8]);
        c[nt] = __builtin_amdgcn_mfma_f32_16x16x32_bf16(a, b, c[nt], 0, 0, 0);
      }
    }
    #pragma unroll
    for (int nt = 0; nt < 4; ++nt) {
      #pragma unroll
      for (int r = 0; r < 4; ++r) {
        int grow = m0 + quad * 4 + r;
        if (grow < N_NODES) x[grow * 64 + nt * 16 + l16] = c[nt][r];
      }
    }
  } else {
    // ---- LDS-binned partition path ----
    int* scnt = (int*)smem;                            // [1000] counters (4KB)
    unsigned int* sbin = (unsigned int*)(smem + 4000); // [1000][BD] bins (40KB)
    const int pj = blockIdx.x - GEMMB;
    const int slice = blockIdx.x & 7;                  // XCD-local cell
    for (int i = t; i < NBUK; i += 256) scnt[i] = 0;
    __syncthreads();
    const int e0 = pj * CHUNK;
    for (int e = e0 + t; e < e0 + CHUNK; e += 256) {
      int s = ei[e], d = ei[N_EDGES + e];
      int b = s / NPB;
      int sl = s - b * NPB;
      unsigned int val = ((unsigned int)d << 8) | (unsigned int)sl;
      int p = atomicAdd(&scnt[b], 1);                  // LDS atomic (cheap)
      if (p < BD) {
        sbin[b * BD + p] = val;
      } else {                                         // rare overflow
        int cell = b * NSL + slice;
        int gp = atomicAdd(&bcnt[cell * 16], 1);
        if (gp < BCAPS) raw[(size_t)cell * BCAPS + gp] = val;
      }
    }
    __syncthreads();
    for (int b = t; b < NBUK; b += 256) {
      int c = scnt[b]; if (c > BD) c = BD;
      if (c > 0) {
        int cell = b * NSL + slice;
        int gp = atomicAdd(&bcnt[cell * 16], c);
        for (int k = 0; k < c; ++k) {
          int idx = gp + k;
          if (idx < BCAPS) raw[(size_t)cell * BCAPS + idx] = sbin[b * BD + k];
        }
      }
    }
  }
}

// ---------------- Kernel 2: el = x@Wl^T, er = x@Wr^T (wave per row) ---------
// Also emits the fp16 copy of x used by the gather (round-2 win).
__global__ __launch_bounds__(256) void k_eler(const float* __restrict__ x,
    const float* __restrict__ Wl, const float* __restrict__ Wr,
    float* __restrict__ el, float* __restrict__ er,
    __half* __restrict__ x16) {
  const int lane = threadIdx.x & 63;
  const int gw = (blockIdx.x * 256 + threadIdx.x) >> 6;
  const int nw = gridDim.x * 4;
  float wl[4], wr[4];
  #pragma unroll
  for (int hh = 0; hh < 4; ++hh) {
    wl[hh] = Wl[hh * 64 + lane];
    wr[hh] = Wr[hh * 64 + lane];
  }
  for (int r = gw; r < N_NODES; r += nw) {
    float xv = x[r * 64 + lane];
    x16[r * 64 + lane] = __float2half(xv);   // coalesced 128B/row store
    float p[4], q[4];
    #pragma unroll
    for (int hh = 0; hh < 4; ++hh) { p[hh] = xv * wl[hh]; q[hh] = xv * wr[hh]; }
    #pragma unroll
    for (int off = 32; off > 0; off >>= 1) {
      #pragma unroll
      for (int hh = 0; hh < 4; ++hh) {
        p[hh] += __shfl_xor(p[hh], off, 64);
        q[hh] += __shfl_xor(q[hh], off, 64);
      }
    }
    if (lane == 0) {
      f32x4 pv = {p[0], p[1], p[2], p[3]};
      f32x4 qv = {q[0], q[1], q[2], q[3]};
      ((f32x4*)el)[r] = pv;
      ((f32x4*)er)[r] = qv;
    }
  }
}

// ---------------- Kernel 3: FUSED CSR + weights + SpMM + ELU ----------------
// One 512-thread block per bucket (1000 blocks). Replaces k_bucket + k_agg:
// the 25.6MB recs global round-trip (whose s_load stream was a ~900cy line
// miss every 4 edges in k_agg) becomes a 32KB LDS CSR (~120cy broadcast).
// Phase 1: histogram from raw. Phase 1.5: exp weights (round to half, then
// accumulate the ROUNDED value into rowsum -- identical numerics to the old
// d0..d3 sums) + scatter into LDS CSR. Phase 2: the known-good gather loop
// (readfirstlane bounds, SGPR row base, unroll-4 -- DO NOT restructure),
// denominators read from LDS rowsum.
// LDS ~32KB -> 4 blocks/CU (thread-capped) = 32 waves/CU.
__global__ __launch_bounds__(512, 8) void k_bagg(const unsigned int* __restrict__ raw,
    const int* __restrict__ bcnt,
    const float* __restrict__ el, const float* __restrict__ er,
    const __half* __restrict__ x16, const float* __restrict__ bvec,
    float* __restrict__ out) {
  __shared__ int dArr[MAXE];          // 10.2KB: dst node per edge
  __shared__ uint2 hArr[MAXE];        // 20.5KB: 4 half weights per edge
  __shared__ int pref[NPB + 1];
  __shared__ int cur[NPB];
  __shared__ float rowsum[NPB][4];
  __shared__ int osl[NSL + 1];
  const int b = blockIdx.x, t = threadIdx.x;
  if (t == 0) {
    int run = 0;
    #pragma unroll
    for (int s = 0; s < NSL; ++s) {
      osl[s] = run;
      int c = bcnt[(b * NSL + s) * 16]; if (c > BCAPS) c = BCAPS;
      run += c;
    }
    osl[NSL] = run;
  }
  if (t <= NPB) pref[t] = 0;
  if (t < NPB) { rowsum[t][0] = 0.f; rowsum[t][1] = 0.f; rowsum[t][2] = 0.f; rowsum[t][3] = 0.f; }
  __syncthreads();
  // ---- phase 1: per-node histogram (coalesced raw read, L2-hot 6.4MB) ----
  for (int s = 0; s < NSL; ++s) {
    const int c = osl[s + 1] - osl[s];
    for (int j = t; j < c; j += 512) {
      unsigned int r = raw[(size_t)(b * NSL + s) * BCAPS + j];
      atomicAdd(&pref[(int)(r & 255u) + 1], 1);
    }
  }
  __syncthreads();
  if (t == 0) {
    int run = 0;
    #pragma unroll
    for (int n = 0; n <= NPB; ++n) { run += pref[n]; pref[n] = run; }
  }
  __syncthreads();
  if (t < NPB) cur[t] = pref[t];
  __syncthreads();
  // ---- phase 1.5: weights + LDS-CSR scatter + rowsum ----
  const int base = b * NPB;
  for (int s = 0; s < NSL; ++s) {
    const int c = osl[s + 1] - osl[s];
    for (int j = t; j < c; j += 512) {
      unsigned int r = raw[(size_t)(b * NSL + s) * BCAPS + j];  // 2nd read: L2-hit
      int sl = (int)(r & 255u);
      int d  = (int)(r >> 8);
      f32x4 a = ((const f32x4*)el)[base + sl];   // L1-resident (800B/bucket)
      f32x4 e = ((const f32x4*)er)[d];           // L2-resident (800 KB)
      float w[4];
      #pragma unroll
      for (int hh = 0; hh < 4; ++hh) {
        float tt = a[hh] + e[hh];
        tt = (tt >= 0.f) ? tt : 0.2f * tt;
        w[hh] = __expf(tt);
      }
      union { __half2 h; unsigned int i; } u01, u23;
      u01.h = __floats2half2_rn(w[0], w[1]);
      u23.h = __floats2half2_rn(w[2], w[3]);
      float2 w01 = __half22float2(u01.h);        // rounded values -> rowsum
      float2 w23 = __half22float2(u23.h);
      int pos = atomicAdd(&cur[sl], 1);
      dArr[pos] = d;
      hArr[pos] = make_uint2(u01.i, u23.i);
      atomicAdd(&rowsum[sl][0], w01.x); atomicAdd(&rowsum[sl][1], w01.y);
      atomicAdd(&rowsum[sl][2], w23.x); atomicAdd(&rowsum[sl][3], w23.y);
    }
  }
  __syncthreads();
  // ---- phase 2: aggregate, wave per node (known-good gather structure) ----
  const int wv = t >> 6, lane = t & 63;
  const float bv = bvec[lane];
  for (int n = wv; n < NPB; n += 8) {
    const int j0 = __builtin_amdgcn_readfirstlane(pref[n]);
    const int j1 = __builtin_amdgcn_readfirstlane(pref[n + 1]);
    float n0 = 0.f, n1 = 0.f, n2 = 0.f, n3 = 0.f;
    #pragma unroll 4
    for (int j = j0; j < j1; ++j) {
      const int dd = __builtin_amdgcn_readfirstlane(dArr[j]);  // LDS broadcast
      uint2 hw = hArr[j];                                      // LDS broadcast
      union { unsigned int i; __half2 h; } u01, u23;
      u01.i = hw.x; u23.i = hw.y;
      float2 f01 = __half22float2(u01.h);
      float2 f23 = __half22float2(u23.h);
      const __half* rowp = x16 + ((size_t)dd << 6);            // SGPR row base
      float xv = __half2float(rowp[lane]);                     // saddr gather
      n0 = fmaf(f01.x, xv, n0); n1 = fmaf(f01.y, xv, n1);
      n2 = fmaf(f23.x, xv, n2); n3 = fmaf(f23.y, xv, n3);
    }
    const float d0 = rowsum[n][0], d1 = rowsum[n][1];
    const float d2 = rowsum[n][2], d3 = rowsum[n][3];
    size_t ob = (size_t)(base + n) * 256 + lane;
    float o;
    o = n0 / fmaxf(d0, 1e-12f) + bv; o = (o > 0.f) ? o : (__expf(o) - 1.f); out[ob      ] = o;
    o = n1 / fmaxf(d1, 1e-12f) + bv; o = (o > 0.f) ? o : (__expf(o) - 1.f); out[ob +  64] = o;
    o = n2 / fmaxf(d2, 1e-12f) + bv; o = (o > 0.f) ? o : (__expf(o) - 1.f); out[ob + 128] = o;
    o = n3 / fmaxf(d3, 1e-12f) + bv; o = (o > 0.f) ? o : (__expf(o) - 1.f); out[ob + 192] = o;
  }
}

// ---------------- Launch ----------------------------------------------------
extern "C" void kernel_launch(void* const* d_in, const int* in_sizes, int n_in,
                              void* d_out, int out_size, void* d_ws, size_t ws_size,
                              hipStream_t stream) {
  const float* h  = (const float*)d_in[0];
  const float* W  = (const float*)d_in[1];
  const float* Wl = (const float*)d_in[2];
  const float* Wr = (const float*)d_in[3];
  const float* b  = (const float*)d_in[4];
  const int*   ei = (const int*)d_in[5];
  float* out = (float*)d_out;   // reference output dtype is float32

  char* ws = (char*)d_ws;
  float*        x    = (float*)       (ws + 0);          // 12,800,000
  float*        el   = (float*)       (ws + 12800000);   //    800,000
  float*        er   = (float*)       (ws + 13600000);   //    800,000
  int*          bcnt = (int*)         (ws + 14400000);   // 8000*64  =    512,000
  unsigned int* raw  = (unsigned int*)(ws + 14912000);   // 8000*320*4 = 10,240,000
  __half*       x16  = (__half*)      (ws + 25152000);   //  6,400,000  (end ~31.6 MB)
  (void)ws_size; (void)in_sizes; (void)n_in; (void)out_size;

  hipMemsetAsync(bcnt, 0, 512000, stream);

  k_xpart  <<<GEMMB + PARTB, 256, 0, stream>>>(h, W, x, ei, bcnt, raw);
  k_eler   <<<782,  256, 0, stream>>>(x, Wl, Wr, el, er, x16);
  k_bagg   <<<NBUK, 512, 0, stream>>>(raw, bcnt, el, er, x16, b, out);
}

// Round 7
// 225.583 us; speedup vs baseline: 1.3845x; 1.3845x over previous
//
#include <hip/hip_runtime.h>
#include <hip/hip_bf16.h>
#include <hip/hip_fp16.h>

#define N_NODES 50000
#define N_EDGES 1600000
#define NPB    50      // nodes per bucket
#define NBUK   1000    // NPB*NBUK == N_NODES
#define NSL    8       // XCD slices
#define BCAPS  320     // slots per (bucket,slice): mean 200, +8.5 sigma
#define BCAPH  1280    // 4*BCAPS, per bucket-half
#define GEMMB  782     // GEMM blocks in fused kernel
#define PARTB  256     // partition blocks in fused kernel
#define CHUNK  6250    // edges per partition block (256*6250 = 1.6M)
#define BD     10      // LDS bin depth (lambda=6.25, overflow ~0.5% -> fallback)

typedef __attribute__((ext_vector_type(8))) short short8;
typedef __attribute__((ext_vector_type(4))) float f32x4;

__device__ __forceinline__ unsigned short f2bf(float f) {
  union { float f; unsigned int i; } v; v.f = f;
  unsigned int i = v.i;
  unsigned int r = i + 0x7FFFu + ((i >> 16) & 1u);
  return (unsigned short)(r >> 16);
}

// ---------------- Kernel 1: FUSED  GEMM(+el/er/x16 epilogue) + partition ----
// Blocks [0,782): bf16-MFMA GEMM producing x16 (half), el, er DIRECTLY from
// the accumulator registers -- the fp32 x buffer and the k_eler kernel are
// gone (saves 12.8MB write + 12.8MB read + one serial launch). el/er use a
// 4-term FMA chain + 16-lane shfl_xor butterfly (fp32 throughout).
// Blocks [782,1038): LDS-binned edge partition (unchanged, round-4 win).
__global__ __launch_bounds__(256) void k_xpart(const float* __restrict__ hmat,
    const float* __restrict__ Wmat,
    const float* __restrict__ Wl, const float* __restrict__ Wr,
    float* __restrict__ el, float* __restrict__ er,
    __half* __restrict__ x16,
    const int* __restrict__ ei, int* __restrict__ bcnt,
    unsigned int* __restrict__ raw) {
  __shared__ __align__(16) char smem[44032];
  const int t = threadIdx.x;
  if (blockIdx.x < GEMMB) {
    // ---- GEMM path ----
    unsigned short* Wt = (unsigned short*)smem;   // Wt[n][k], row stride 264
    for (int idx = t; idx < 64 * 256; idx += 256) {
      int k = idx >> 6, n = idx & 63;
      Wt[n * 264 + k] = f2bf(Wmat[idx]);
    }
    __syncthreads();
    const int wave = t >> 6, lane = t & 63;
    const int quad = lane >> 4, l16 = lane & 15;
    const int m0 = blockIdx.x * 64 + wave * 16;
    int arow = m0 + l16; if (arow >= N_NODES) arow = N_NODES - 1;
    f32x4 c[4] = {{0,0,0,0},{0,0,0,0},{0,0,0,0},{0,0,0,0}};
    const float* aptr = hmat + (size_t)arow * 256 + quad * 8;
    #pragma unroll
    for (int kb = 0; kb < 8; ++kb) {
      f32x4 a0 = *(const f32x4*)(aptr + kb * 32);
      f32x4 a1 = *(const f32x4*)(aptr + kb * 32 + 4);
      short8 a;
      a[0] = (short)f2bf(a0[0]); a[1] = (short)f2bf(a0[1]);
      a[2] = (short)f2bf(a0[2]); a[3] = (short)f2bf(a0[3]);
      a[4] = (short)f2bf(a1[0]); a[5] = (short)f2bf(a1[1]);
      a[6] = (short)f2bf(a1[2]); a[7] = (short)f2bf(a1[3]);
      #pragma unroll
      for (int nt = 0; nt < 4; ++nt) {
        int n = nt * 16 + l16;
        short8 b = *(const short8*)(&Wt[n * 264 + kb * 32 + quad * 8]);
        c[nt] = __builtin_amdgcn_mfma_f32_16x16x32_bf16(a, b, c[nt], 0, 0, 0);
      }
    }
    // ---- epilogue: x16 + el/er from registers ----
    float wlv[4][4], wrv[4][4];   // [h][nt] slice this lane needs (L1-hot)
    #pragma unroll
    for (int h = 0; h < 4; ++h)
      #pragma unroll
      for (int nt = 0; nt < 4; ++nt) {
        wlv[h][nt] = Wl[h * 64 + nt * 16 + l16];
        wrv[h][nt] = Wr[h * 64 + nt * 16 + l16];
      }
    #pragma unroll
    for (int r = 0; r < 4; ++r) {
      const int grow = m0 + quad * 4 + r;
      const bool ok = grow < N_NODES;
      #pragma unroll
      for (int nt = 0; nt < 4; ++nt)
        if (ok) x16[grow * 64 + nt * 16 + l16] = __float2half(c[nt][r]);
      #pragma unroll
      for (int h = 0; h < 4; ++h) {
        float pl = c[0][r] * wlv[h][0];
        pl = fmaf(c[1][r], wlv[h][1], pl);
        pl = fmaf(c[2][r], wlv[h][2], pl);
        pl = fmaf(c[3][r], wlv[h][3], pl);
        float pr = c[0][r] * wrv[h][0];
        pr = fmaf(c[1][r], wrv[h][1], pr);
        pr = fmaf(c[2][r], wrv[h][2], pr);
        pr = fmaf(c[3][r], wrv[h][3], pr);
        #pragma unroll
        for (int off = 1; off < 16; off <<= 1) {   // 16-lane tree (within quad)
          pl += __shfl_xor(pl, off, 64);
          pr += __shfl_xor(pr, off, 64);
        }
        if (ok && l16 == 0) { el[grow * 4 + h] = pl; er[grow * 4 + h] = pr; }
      }
    }
  } else {
    // ---- LDS-binned partition path (unchanged) ----
    int* scnt = (int*)smem;                            // [1000] counters (4KB)
    unsigned int* sbin = (unsigned int*)(smem + 4000); // [1000][BD] bins (40KB)
    const int pj = blockIdx.x - GEMMB;
    const int slice = blockIdx.x & 7;                  // XCD-local cell
    for (int i = t; i < NBUK; i += 256) scnt[i] = 0;
    __syncthreads();
    const int e0 = pj * CHUNK;
    for (int e = e0 + t; e < e0 + CHUNK; e += 256) {
      int s = ei[e], d = ei[N_EDGES + e];
      int b = s / NPB;
      int sl = s - b * NPB;
      unsigned int val = ((unsigned int)d << 8) | (unsigned int)sl;
      int p = atomicAdd(&scnt[b], 1);                  // LDS atomic (cheap)
      if (p < BD) {
        sbin[b * BD + p] = val;
      } else {                                         // rare overflow
        int cell = b * NSL + slice;
        int gp = atomicAdd(&bcnt[cell * 16], 1);
        if (gp < BCAPS) raw[(size_t)cell * BCAPS + gp] = val;
      }
    }
    __syncthreads();
    for (int b = t; b < NBUK; b += 256) {
      int c = scnt[b]; if (c > BD) c = BD;
      if (c > 0) {
        int cell = b * NSL + slice;
        int gp = atomicAdd(&bcnt[cell * 16], c);
        for (int k = 0; k < c; ++k) {
          int idx = gp + k;
          if (idx < BCAPS) raw[(size_t)cell * BCAPS + idx] = sbin[b * BD + k];
        }
      }
    }
  }
}

// ---------------- Kernel 2: per-bucket-half CSR + edge weights --------------
// Grid 2000: b = blk>>1, half = blk&1 handles slices 4*half..4*half+3.
// (Round-5 known-good; k_bagg fusion of this + k_agg regressed -> keep split.)
__global__ __launch_bounds__(256) void k_bucket(const unsigned int* __restrict__ raw,
    const int* __restrict__ bcnt,
    const float* __restrict__ el, const float* __restrict__ er,
    int4* __restrict__ recs, int* __restrict__ rs_s, int* __restrict__ rs_e) {
  __shared__ unsigned int sraw[BCAPH];
  __shared__ int pref[NPB + 1];
  __shared__ int cur[NPB];
  const int b = blockIdx.x >> 1, H = blockIdx.x & 1, t = threadIdx.x;
  const int s0 = H * 4;
  int c0 = bcnt[(b * NSL + s0 + 0) * 16]; if (c0 > BCAPS) c0 = BCAPS;
  int c1 = bcnt[(b * NSL + s0 + 1) * 16]; if (c1 > BCAPS) c1 = BCAPS;
  int c2 = bcnt[(b * NSL + s0 + 2) * 16]; if (c2 > BCAPS) c2 = BCAPS;
  int c3 = bcnt[(b * NSL + s0 + 3) * 16]; if (c3 > BCAPS) c3 = BCAPS;
  const int o1 = c0, o2 = c0 + c1, o3 = c0 + c1 + c2, cnt = o3 + c3;
  if (t <= NPB) pref[t] = 0;
  __syncthreads();
  for (int j = t; j < c0; j += 256) { unsigned int r = raw[(size_t)(b*NSL+s0+0)*BCAPS + j]; sraw[j]      = r; atomicAdd(&pref[(int)(r & 255u) + 1], 1); }
  for (int j = t; j < c1; j += 256) { unsigned int r = raw[(size_t)(b*NSL+s0+1)*BCAPS + j]; sraw[o1 + j] = r; atomicAdd(&pref[(int)(r & 255u) + 1], 1); }
  for (int j = t; j < c2; j += 256) { unsigned int r = raw[(size_t)(b*NSL+s0+2)*BCAPS + j]; sraw[o2 + j] = r; atomicAdd(&pref[(int)(r & 255u) + 1], 1); }
  for (int j = t; j < c3; j += 256) { unsigned int r = raw[(size_t)(b*NSL+s0+3)*BCAPS + j]; sraw[o3 + j] = r; atomicAdd(&pref[(int)(r & 255u) + 1], 1); }
  __syncthreads();
  if (t == 0) {
    int run = 0;
    #pragma unroll
    for (int n = 0; n <= NPB; ++n) { run += pref[n]; pref[n] = run; }
  }
  __syncthreads();
  const int wbase = (b * 2 + H) * BCAPH;   // this half's window in recs
  if (t < NPB) {
    cur[t] = pref[t];
    rs_s[H * N_NODES + b * NPB + t] = wbase + pref[t];
    rs_e[H * N_NODES + b * NPB + t] = wbase + pref[t + 1];
  }
  __syncthreads();
  const int base = b * NPB;
  for (int j = t; j < cnt; j += 256) {
    unsigned int r = sraw[j];
    int sl = (int)(r & 255u);
    int d  = (int)(r >> 8);
    int pos = atomicAdd(&cur[sl], 1);
    f32x4 a = ((const f32x4*)el)[base + sl];   // L1-resident (800B/bucket)
    f32x4 e = ((const f32x4*)er)[d];           // L2-resident (800 KB)
    float w[4];
    #pragma unroll
    for (int hh = 0; hh < 4; ++hh) {
      float tt = a[hh] + e[hh];
      tt = (tt >= 0.f) ? tt : 0.2f * tt;
      w[hh] = __expf(tt);
    }
    union { __half2 h; int i; } u01, u23;
    u01.h = __floats2half2_rn(w[0], w[1]);
    u23.h = __floats2half2_rn(w[2], w[3]);
    int4 rc; rc.x = d; rc.y = u01.i; rc.z = u23.i; rc.w = 0;
    recs[(size_t)wbase + pos] = rc;            // scattered within 20KB window
  }
}

// ---------------- Kernel 3: fused normalize + SpMM + ELU --------------------
// One wave per node; unroll-4 schedule preserved (known-good); j0/j1 hoisted
// to SGPR via readfirstlane -> recs[j] wave-uniform (s_load path), gather is
// saddr-form with SGPR row base. Do NOT restructure this loop.
__global__ __launch_bounds__(256) void k_agg(const __half* __restrict__ x16,
    const int* __restrict__ rs_s, const int* __restrict__ rs_e,
    const int4* __restrict__ recs,
    const float* __restrict__ bvec, float* __restrict__ out) {
  const int node = (blockIdx.x * 256 + threadIdx.x) >> 6;
  const int lane = threadIdx.x & 63;
  if (node >= N_NODES) return;
  float n0 = 0.f, n1 = 0.f, n2 = 0.f, n3 = 0.f;
  float d0 = 0.f, d1 = 0.f, d2 = 0.f, d3 = 0.f;
  #pragma unroll
  for (int hf = 0; hf < 2; ++hf) {
    const int j0 = __builtin_amdgcn_readfirstlane(rs_s[hf * N_NODES + node]);
    const int j1 = __builtin_amdgcn_readfirstlane(rs_e[hf * N_NODES + node]);
    #pragma unroll 4
    for (int j = j0; j < j1; ++j) {
      int4 rec = recs[j];               // uniform addr -> s_load_dwordx4
      union { int i; __half2 h; } u01, u23;
      u01.i = rec.y; u23.i = rec.z;
      float2 f01 = __half22float2(u01.h);
      float2 f23 = __half22float2(u23.h);
      const __half* rowp = x16 + ((size_t)rec.x << 6);   // SGPR row base
      float xv = __half2float(rowp[lane]);               // saddr-form gather
      d0 += f01.x; d1 += f01.y; d2 += f23.x; d3 += f23.y;
      n0 = fmaf(f01.x, xv, n0); n1 = fmaf(f01.y, xv, n1);
      n2 = fmaf(f23.x, xv, n2); n3 = fmaf(f23.y, xv, n3);
    }
  }
  float bv = bvec[lane];
  size_t ob = (size_t)node * 256 + lane;
  float o;
  o = n0 / fmaxf(d0, 1e-12f) + bv; o = (o > 0.f) ? o : (__expf(o) - 1.f); out[ob      ] = o;
  o = n1 / fmaxf(d1, 1e-12f) + bv; o = (o > 0.f) ? o : (__expf(o) - 1.f); out[ob +  64] = o;
  o = n2 / fmaxf(d2, 1e-12f) + bv; o = (o > 0.f) ? o : (__expf(o) - 1.f); out[ob + 128] = o;
  o = n3 / fmaxf(d3, 1e-12f) + bv; o = (o > 0.f) ? o : (__expf(o) - 1.f); out[ob + 192] = o;
}

// ---------------- Launch ----------------------------------------------------
extern "C" void kernel_launch(void* const* d_in, const int* in_sizes, int n_in,
                              void* d_out, int out_size, void* d_ws, size_t ws_size,
                              hipStream_t stream) {
  const float* h  = (const float*)d_in[0];
  const float* W  = (const float*)d_in[1];
  const float* Wl = (const float*)d_in[2];
  const float* Wr = (const float*)d_in[3];
  const float* b  = (const float*)d_in[4];
  const int*   ei = (const int*)d_in[5];
  float* out = (float*)d_out;   // reference output dtype is float32

  char* ws = (char*)d_ws;
  float*        el   = (float*)       (ws + 0);          //    800,000
  float*        er   = (float*)       (ws + 800000);     //    800,000
  int*          bcnt = (int*)         (ws + 1600000);    //    512,000
  unsigned int* raw  = (unsigned int*)(ws + 2112000);    // 10,240,000
  int4*         recs = (int4*)        (ws + 12352000);   // 40,960,000
  int*          rs_s = (int*)         (ws + 53312000);   //    400,000
  int*          rs_e = (int*)         (ws + 53712000);   //    400,000
  __half*       x16  = (__half*)      (ws + 54112000);   //  6,400,000  (end ~60.5 MB)
  (void)ws_size; (void)in_sizes; (void)n_in; (void)out_size;

  hipMemsetAsync(bcnt, 0, 512000, stream);

  k_xpart  <<<GEMMB + PARTB, 256, 0, stream>>>(h, W, Wl, Wr, el, er, x16, ei, bcnt, raw);
  k_bucket <<<2000,  256, 0, stream>>>(raw, bcnt, el, er, recs, rs_s, rs_e);
  k_agg    <<<12500, 256, 0, stream>>>(x16, rs_s, rs_e, recs, b, out);
}

// Round 8
// 221.852 us; speedup vs baseline: 1.4078x; 1.0168x over previous
//
#include <hip/hip_runtime.h>
#include <hip/hip_bf16.h>
#include <hip/hip_fp16.h>

#define N_NODES 50000
#define N_EDGES 1600000
#define NPB    50      // nodes per bucket
#define NBUK   1000    // NPB*NBUK == N_NODES
#define NSL    8       // XCD slices
#define BCAPS  320     // slots per (bucket,slice): mean 200, +8.5 sigma
#define BCAPH  1280    // 4*BCAPS, per bucket-half
#define GEMMB  782     // GEMM blocks in fused kernel
#define PARTB  512     // partition blocks in fused kernel (first in grid!)
#define CHUNK  3125    // edges per partition block (512*3125 = 1.6M)
#define BD     8       // LDS bin depth (lambda=3.1, overflow ~0.5% -> fallback)

typedef __attribute__((ext_vector_type(8))) short short8;
typedef __attribute__((ext_vector_type(4))) float f32x4;

__device__ __forceinline__ unsigned short f2bf(float f) {
  union { float f; unsigned int i; } v; v.f = f;
  unsigned int i = v.i;
  unsigned int r = i + 0x7FFFu + ((i >> 16) & 1u);
  return (unsigned short)(r >> 16);
}

// ---------------- Kernel 1: FUSED  partition + GEMM(+el/er/x16 epilogue) ----
// Blocks [0,512): LDS-binned edge partition -- FIRST in the grid so they are
// resident from cycle 0 and truly overlap the GEMM (round-6 had them last:
// the partition tail ran alone at 12.5% occupancy after the GEMM retired).
// Blocks [512,1294): bf16-MFMA GEMM producing x16/el/er from registers.
// LDS union 36KB (BD=8) -> 4 blocks/CU for both paths.
__global__ __launch_bounds__(256) void k_xpart(const float* __restrict__ hmat,
    const float* __restrict__ Wmat,
    const float* __restrict__ Wl, const float* __restrict__ Wr,
    float* __restrict__ el, float* __restrict__ er,
    __half* __restrict__ x16,
    const int* __restrict__ ei, int* __restrict__ bcnt,
    unsigned int* __restrict__ raw) {
  __shared__ __align__(16) char smem[36864];
  const int t = threadIdx.x;
  if (blockIdx.x >= PARTB) {
    // ---- GEMM path ----
    unsigned short* Wt = (unsigned short*)smem;   // Wt[n][k], row stride 264
    for (int idx = t; idx < 64 * 256; idx += 256) {
      int k = idx >> 6, n = idx & 63;
      Wt[n * 264 + k] = f2bf(Wmat[idx]);
    }
    __syncthreads();
    const int wave = t >> 6, lane = t & 63;
    const int quad = lane >> 4, l16 = lane & 15;
    const int m0 = (blockIdx.x - PARTB) * 64 + wave * 16;
    int arow = m0 + l16; if (arow >= N_NODES) arow = N_NODES - 1;
    f32x4 c[4] = {{0,0,0,0},{0,0,0,0},{0,0,0,0},{0,0,0,0}};
    const float* aptr = hmat + (size_t)arow * 256 + quad * 8;
    #pragma unroll
    for (int kb = 0; kb < 8; ++kb) {
      f32x4 a0 = *(const f32x4*)(aptr + kb * 32);
      f32x4 a1 = *(const f32x4*)(aptr + kb * 32 + 4);
      short8 a;
      a[0] = (short)f2bf(a0[0]); a[1] = (short)f2bf(a0[1]);
      a[2] = (short)f2bf(a0[2]); a[3] = (short)f2bf(a0[3]);
      a[4] = (short)f2bf(a1[0]); a[5] = (short)f2bf(a1[1]);
      a[6] = (short)f2bf(a1[2]); a[7] = (short)f2bf(a1[3]);
      #pragma unroll
      for (int nt = 0; nt < 4; ++nt) {
        int n = nt * 16 + l16;
        short8 b = *(const short8*)(&Wt[n * 264 + kb * 32 + quad * 8]);
        c[nt] = __builtin_amdgcn_mfma_f32_16x16x32_bf16(a, b, c[nt], 0, 0, 0);
      }
    }
    // ---- epilogue: x16 + el/er from registers (round-6 win) ----
    float wlv[4][4], wrv[4][4];   // [h][nt] slice this lane needs (L1-hot)
    #pragma unroll
    for (int h = 0; h < 4; ++h)
      #pragma unroll
      for (int nt = 0; nt < 4; ++nt) {
        wlv[h][nt] = Wl[h * 64 + nt * 16 + l16];
        wrv[h][nt] = Wr[h * 64 + nt * 16 + l16];
      }
    #pragma unroll
    for (int r = 0; r < 4; ++r) {
      const int grow = m0 + quad * 4 + r;
      const bool ok = grow < N_NODES;
      #pragma unroll
      for (int nt = 0; nt < 4; ++nt)
        if (ok) x16[grow * 64 + nt * 16 + l16] = __float2half(c[nt][r]);
      #pragma unroll
      for (int h = 0; h < 4; ++h) {
        float pl = c[0][r] * wlv[h][0];
        pl = fmaf(c[1][r], wlv[h][1], pl);
        pl = fmaf(c[2][r], wlv[h][2], pl);
        pl = fmaf(c[3][r], wlv[h][3], pl);
        float pr = c[0][r] * wrv[h][0];
        pr = fmaf(c[1][r], wrv[h][1], pr);
        pr = fmaf(c[2][r], wrv[h][2], pr);
        pr = fmaf(c[3][r], wrv[h][3], pr);
        #pragma unroll
        for (int off = 1; off < 16; off <<= 1) {   // 16-lane tree (within quad)
          pl += __shfl_xor(pl, off, 64);
          pr += __shfl_xor(pr, off, 64);
        }
        if (ok && l16 == 0) { el[grow * 4 + h] = pl; er[grow * 4 + h] = pr; }
      }
    }
  } else {
    // ---- LDS-binned partition path ----
    int* scnt = (int*)smem;                            // [1000] counters (4KB)
    unsigned int* sbin = (unsigned int*)(smem + 4000); // [1000][BD] bins (32KB)
    const int pj = blockIdx.x;
    const int slice = blockIdx.x & 7;                  // XCD-local cell
    for (int i = t; i < NBUK; i += 256) scnt[i] = 0;
    __syncthreads();
    const int e0 = pj * CHUNK;
    for (int e = e0 + t; e < e0 + CHUNK; e += 256) {
      int s = ei[e], d = ei[N_EDGES + e];
      int b = s / NPB;
      int sl = s - b * NPB;
      unsigned int val = ((unsigned int)d << 8) | (unsigned int)sl;
      int p = atomicAdd(&scnt[b], 1);                  // LDS atomic (cheap)
      if (p < BD) {
        sbin[b * BD + p] = val;
      } else {                                         // rare overflow
        int cell = b * NSL + slice;
        int gp = atomicAdd(&bcnt[cell * 16], 1);
        if (gp < BCAPS) raw[(size_t)cell * BCAPS + gp] = val;
      }
    }
    __syncthreads();
    for (int b = t; b < NBUK; b += 256) {
      int c = scnt[b]; if (c > BD) c = BD;
      if (c > 0) {
        int cell = b * NSL + slice;
        int gp = atomicAdd(&bcnt[cell * 16], c);
        for (int k = 0; k < c; ++k) {
          int idx = gp + k;
          if (idx < BCAPS) raw[(size_t)cell * BCAPS + idx] = sbin[b * BD + k];
        }
      }
    }
  }
}

// ---------------- Kernel 2: per-bucket-half CSR + edge weights --------------
// Grid 2000: b = blk>>1, half = blk&1 handles slices 4*half..4*half+3.
// (Round-5 known-good; k_bagg fusion of this + k_agg regressed -> keep split.)
__global__ __launch_bounds__(256) void k_bucket(const unsigned int* __restrict__ raw,
    const int* __restrict__ bcnt,
    const float* __restrict__ el, const float* __restrict__ er,
    int4* __restrict__ recs, int* __restrict__ rs_s, int* __restrict__ rs_e) {
  __shared__ unsigned int sraw[BCAPH];
  __shared__ int pref[NPB + 1];
  __shared__ int cur[NPB];
  const int b = blockIdx.x >> 1, H = blockIdx.x & 1, t = threadIdx.x;
  const int s0 = H * 4;
  int c0 = bcnt[(b * NSL + s0 + 0) * 16]; if (c0 > BCAPS) c0 = BCAPS;
  int c1 = bcnt[(b * NSL + s0 + 1) * 16]; if (c1 > BCAPS) c1 = BCAPS;
  int c2 = bcnt[(b * NSL + s0 + 2) * 16]; if (c2 > BCAPS) c2 = BCAPS;
  int c3 = bcnt[(b * NSL + s0 + 3) * 16]; if (c3 > BCAPS) c3 = BCAPS;
  const int o1 = c0, o2 = c0 + c1, o3 = c0 + c1 + c2, cnt = o3 + c3;
  if (t <= NPB) pref[t] = 0;
  __syncthreads();
  for (int j = t; j < c0; j += 256) { unsigned int r = raw[(size_t)(b*NSL+s0+0)*BCAPS + j]; sraw[j]      = r; atomicAdd(&pref[(int)(r & 255u) + 1], 1); }
  for (int j = t; j < c1; j += 256) { unsigned int r = raw[(size_t)(b*NSL+s0+1)*BCAPS + j]; sraw[o1 + j] = r; atomicAdd(&pref[(int)(r & 255u) + 1], 1); }
  for (int j = t; j < c2; j += 256) { unsigned int r = raw[(size_t)(b*NSL+s0+2)*BCAPS + j]; sraw[o2 + j] = r; atomicAdd(&pref[(int)(r & 255u) + 1], 1); }
  for (int j = t; j < c3; j += 256) { unsigned int r = raw[(size_t)(b*NSL+s0+3)*BCAPS + j]; sraw[o3 + j] = r; atomicAdd(&pref[(int)(r & 255u) + 1], 1); }
  __syncthreads();
  if (t == 0) {
    int run = 0;
    #pragma unroll
    for (int n = 0; n <= NPB; ++n) { run += pref[n]; pref[n] = run; }
  }
  __syncthreads();
  const int wbase = (b * 2 + H) * BCAPH;   // this half's window in recs
  if (t < NPB) {
    cur[t] = pref[t];
    rs_s[H * N_NODES + b * NPB + t] = wbase + pref[t];
    rs_e[H * N_NODES + b * NPB + t] = wbase + pref[t + 1];
  }
  __syncthreads();
  const int base = b * NPB;
  for (int j = t; j < cnt; j += 256) {
    unsigned int r = sraw[j];
    int sl = (int)(r & 255u);
    int d  = (int)(r >> 8);
    int pos = atomicAdd(&cur[sl], 1);
    f32x4 a = ((const f32x4*)el)[base + sl];   // L1-resident (800B/bucket)
    f32x4 e = ((const f32x4*)er)[d];           // L2-resident (800 KB)
    float w[4];
    #pragma unroll
    for (int hh = 0; hh < 4; ++hh) {
      float tt = a[hh] + e[hh];
      tt = (tt >= 0.f) ? tt : 0.2f * tt;
      w[hh] = __expf(tt);
    }
    union { __half2 h; int i; } u01, u23;
    u01.h = __floats2half2_rn(w[0], w[1]);
    u23.h = __floats2half2_rn(w[2], w[3]);
    int4 rc; rc.x = d; rc.y = u01.i; rc.z = u23.i; rc.w = 0;
    recs[(size_t)wbase + pos] = rc;            // scattered within 20KB window
  }
}

// ---------------- Kernel 3: fused normalize + SpMM + ELU --------------------
// One wave per node; unroll-4 schedule preserved (known-good); j0/j1 hoisted
// to SGPR via readfirstlane -> recs[j] wave-uniform (s_load path), gather is
// saddr-form with SGPR row base. Do NOT restructure this loop.
__global__ __launch_bounds__(256) void k_agg(const __half* __restrict__ x16,
    const int* __restrict__ rs_s, const int* __restrict__ rs_e,
    const int4* __restrict__ recs,
    const float* __restrict__ bvec, float* __restrict__ out) {
  const int node = (blockIdx.x * 256 + threadIdx.x) >> 6;
  const int lane = threadIdx.x & 63;
  if (node >= N_NODES) return;
  float n0 = 0.f, n1 = 0.f, n2 = 0.f, n3 = 0.f;
  float d0 = 0.f, d1 = 0.f, d2 = 0.f, d3 = 0.f;
  #pragma unroll
  for (int hf = 0; hf < 2; ++hf) {
    const int j0 = __builtin_amdgcn_readfirstlane(rs_s[hf * N_NODES + node]);
    const int j1 = __builtin_amdgcn_readfirstlane(rs_e[hf * N_NODES + node]);
    #pragma unroll 4
    for (int j = j0; j < j1; ++j) {
      int4 rec = recs[j];               // uniform addr -> s_load_dwordx4
      union { int i; __half2 h; } u01, u23;
      u01.i = rec.y; u23.i = rec.z;
      float2 f01 = __half22float2(u01.h);
      float2 f23 = __half22float2(u23.h);
      const __half* rowp = x16 + ((size_t)rec.x << 6);   // SGPR row base
      float xv = __half2float(rowp[lane]);               // saddr-form gather
      d0 += f01.x; d1 += f01.y; d2 += f23.x; d3 += f23.y;
      n0 = fmaf(f01.x, xv, n0); n1 = fmaf(f01.y, xv, n1);
      n2 = fmaf(f23.x, xv, n2); n3 = fmaf(f23.y, xv, n3);
    }
  }
  float bv = bvec[lane];
  size_t ob = (size_t)node * 256 + lane;
  float o;
  o = n0 / fmaxf(d0, 1e-12f) + bv; o = (o > 0.f) ? o : (__expf(o) - 1.f); out[ob      ] = o;
  o = n1 / fmaxf(d1, 1e-12f) + bv; o = (o > 0.f) ? o : (__expf(o) - 1.f); out[ob +  64] = o;
  o = n2 / fmaxf(d2, 1e-12f) + bv; o = (o > 0.f) ? o : (__expf(o) - 1.f); out[ob + 128] = o;
  o = n3 / fmaxf(d3, 1e-12f) + bv; o = (o > 0.f) ? o : (__expf(o) - 1.f); out[ob + 192] = o;
}

// ---------------- Launch ----------------------------------------------------
extern "C" void kernel_launch(void* const* d_in, const int* in_sizes, int n_in,
                              void* d_out, int out_size, void* d_ws, size_t ws_size,
                              hipStream_t stream) {
  const float* h  = (const float*)d_in[0];
  const float* W  = (const float*)d_in[1];
  const float* Wl = (const float*)d_in[2];
  const float* Wr = (const float*)d_in[3];
  const float* b  = (const float*)d_in[4];
  const int*   ei = (const int*)d_in[5];
  float* out = (float*)d_out;   // reference output dtype is float32

  char* ws = (char*)d_ws;
  float*        el   = (float*)       (ws + 0);          //    800,000
  float*        er   = (float*)       (ws + 800000);     //    800,000
  int*          bcnt = (int*)         (ws + 1600000);    //    512,000
  unsigned int* raw  = (unsigned int*)(ws + 2112000);    // 10,240,000
  int4*         recs = (int4*)        (ws + 12352000);   // 40,960,000
  int*          rs_s = (int*)         (ws + 53312000);   //    400,000
  int*          rs_e = (int*)         (ws + 53712000);   //    400,000
  __half*       x16  = (__half*)      (ws + 54112000);   //  6,400,000  (end ~60.5 MB)
  (void)ws_size; (void)in_sizes; (void)n_in; (void)out_size;

  hipMemsetAsync(bcnt, 0, 512000, stream);

  k_xpart  <<<PARTB + GEMMB, 256, 0, stream>>>(h, W, Wl, Wr, el, er, x16, ei, bcnt, raw);
  k_bucket <<<2000,  256, 0, stream>>>(raw, bcnt, el, er, recs, rs_s, rs_e);
  k_agg    <<<12500, 256, 0, stream>>>(x16, rs_s, rs_e, recs, b, out);
}